// Round 2
// baseline (616.613 us; speedup 1.0000x reference)
//
#include <hip/hip_runtime.h>
#include <hip/hip_bf16.h>

// BasicCae: x[256,28224] fp32, W_enc[1500,28224], b_enc[1500], W_dec[28224,1500], b_dec[28224]
// out: y_out[256,28224] fp32 ++ jac_reg scalar (at index 7225344)
//
// R2: barrier-free GEMMs. MFMA A/B fragments are loaded DIRECTLY from global
// (lane l15 -> row, quad*8 -> contiguous K), fp32->bf16 converted in-register
// via v_perm pack. No LDS, no __syncthreads in the GEMM hot loops -> no
// vmcnt(0) drains; latency hidden by independent waves.

#define BATCH 256
#define IN    28224
#define FEAT  1500
#define FPAD  1536

typedef __attribute__((ext_vector_type(8))) short short8;   // 8 bf16
typedef __attribute__((ext_vector_type(4))) float f32x4;    // MFMA acc

// pack two fp32 -> two bf16 (round-half-up) in one u32: 2 adds + 1 v_perm
__device__ __forceinline__ unsigned pack2(float lo, float hi) {
    unsigned a = __float_as_uint(lo) + 0x8000u;
    unsigned b = __float_as_uint(hi) + 0x8000u;
    return __builtin_amdgcn_perm(b, a, 0x07060302);  // (hi16(b)<<16)|hi16(a)
}

__device__ __forceinline__ short8 cvt8(const float4 v0, const float4 v1) {
    union { short8 s; unsigned u[4]; } r;
    r.u[0] = pack2(v0.x, v0.y);
    r.u[1] = pack2(v0.z, v0.w);
    r.u[2] = pack2(v1.x, v1.y);
    r.u[3] = pack2(v1.z, v1.w);
    return r.s;
}

// ---------------- x fp32 -> bf16, once ----------------
__global__ __launch_bounds__(256) void cvt_x(const float* __restrict__ x,
                                             unsigned short* __restrict__ xbf) {
    int idx = blockIdx.x * 256 + threadIdx.x;       // 7056*256 == 28224*256/4 exactly
    float4 v = ((const float4*)x)[idx];
    ((uint2*)xbf)[idx] = make_uint2(pack2(v.x, v.y), pack2(v.z, v.w));
}

// ---------------- Encoder: preact += x . W_enc^T (split-K atomics) ----------------
// grid = (24 N-tiles, 42 K-splits). Block = 4 waves; wave w does rows [w*64, w*64+64).
// Wave 0 also accumulates row_norm2 from the exact fp32 W values (each W element
// is touched by wave 0 of exactly one block).
__global__ __launch_bounds__(256) void enc_gemm(const unsigned short* __restrict__ xbf,
                                                const float* __restrict__ We,
                                                float* __restrict__ preact,
                                                float* __restrict__ rn2) {
    const int n0   = blockIdx.x * 64;
    const int kb   = blockIdx.y * 672;              // 42 * 672 = 28224
    const int t    = threadIdx.x;
    const int lane = t & 63;
    const int w    = t >> 6;
    const int l15  = lane & 15;
    const int quad = lane >> 4;
    const int m0   = w * 64;

    const unsigned short* ap[4];
#pragma unroll
    for (int mt = 0; mt < 4; ++mt)
        ap[mt] = xbf + (long)(m0 + mt * 16 + l15) * IN + quad * 8 + kb;

    const float* bp[4];
    int fcol[4];
#pragma unroll
    for (int nt = 0; nt < 4; ++nt) {
        int f = n0 + nt * 16 + l15;
        fcol[nt] = f;
        int fc = f < FEAT ? f : FEAT - 1;           // clamp; garbage cols never stored
        bp[nt] = We + (long)fc * IN + quad * 8 + kb;
    }

    f32x4 acc[4][4];
#pragma unroll
    for (int mt = 0; mt < 4; ++mt)
#pragma unroll
        for (int nt = 0; nt < 4; ++nt) { f32x4 z = {0.f, 0.f, 0.f, 0.f}; acc[mt][nt] = z; }
    float rsq[4] = {0.f, 0.f, 0.f, 0.f};

    for (int k = 0; k < 672; k += 32) {
        short8 a[4];
#pragma unroll
        for (int mt = 0; mt < 4; ++mt)
            a[mt] = *(const short8*)(ap[mt] + k);
        short8 bb[4];
#pragma unroll
        for (int nt = 0; nt < 4; ++nt) {
            const float4 b0 = *(const float4*)(bp[nt] + k);
            const float4 b1 = *(const float4*)(bp[nt] + k + 4);
            bb[nt] = cvt8(b0, b1);
            if (w == 0) {
                rsq[nt] += b0.x * b0.x + b0.y * b0.y + b0.z * b0.z + b0.w * b0.w
                         + b1.x * b1.x + b1.y * b1.y + b1.z * b1.z + b1.w * b1.w;
            }
        }
#pragma unroll
        for (int mt = 0; mt < 4; ++mt)
#pragma unroll
            for (int nt = 0; nt < 4; ++nt)
                acc[mt][nt] = __builtin_amdgcn_mfma_f32_16x16x32_bf16(a[mt], bb[nt], acc[mt][nt], 0, 0, 0);
    }

    // split-K partials -> fp32 atomics
#pragma unroll
    for (int nt = 0; nt < 4; ++nt) {
        const int col = fcol[nt];
        if (col < FEAT) {
#pragma unroll
            for (int mt = 0; mt < 4; ++mt) {
                float* p = preact + (long)(m0 + mt * 16 + quad * 4) * FEAT + col;
#pragma unroll
                for (int r = 0; r < 4; ++r) atomicAdd(p + (long)r * FEAT, acc[mt][nt][r]);
            }
        }
    }

    if (w == 0) {
#pragma unroll
        for (int nt = 0; nt < 4; ++nt) {
            float v = rsq[nt];
            v += __shfl_xor(v, 16);
            v += __shfl_xor(v, 32);
            if (quad == 0 && fcol[nt] < FEAT) atomicAdd(&rn2[fcol[nt]], v);
        }
    }
}

// ---------------- Activation + Jacobian regularizer ----------------
__global__ __launch_bounds__(256) void act_jac(const float* __restrict__ preact,
                                               const float* __restrict__ be,
                                               const float* __restrict__ rn2,
                                               unsigned short* __restrict__ yenc,
                                               float* __restrict__ jac) {
    const int b = blockIdx.y;
    const int f = blockIdx.x * 256 + threadIdx.x;   // 0..1535
    float local = 0.0f;
    unsigned short h = 0;
    if (f < FEAT) {
        float p = preact[b * FEAT + f] + be[f];
        float y = 1.0f / (1.0f + __expf(-p));
        unsigned u = __float_as_uint(y);
        h = (unsigned short)((u + 0x7FFFu + ((u >> 16) & 1u)) >> 16);
        float s = y * (1.0f - y);
        local = s * s * rn2[f];
    }
    yenc[b * FPAD + f] = h;                         // zero-pads cols 1500..1535

    float v = local;
#pragma unroll
    for (int off = 32; off > 0; off >>= 1) v += __shfl_down(v, off);
    __shared__ float red[4];
    if ((threadIdx.x & 63) == 0) red[threadIdx.x >> 6] = v;
    __syncthreads();
    if (threadIdx.x == 0) atomicAdd(jac, red[0] + red[1] + red[2] + red[3]);
}

// ---------------- Decoder: out = sigmoid(yenc . W_dec^T + b_dec) ----------------
// grid = 441 N-tiles; block = 4 waves, wave tile 64x64; barrier-free, K=1500
// handled as 46 full steps + 1 clamped tail step (yenc pad zeros cancel garbage).
__global__ __launch_bounds__(256) void dec_gemm(const unsigned short* __restrict__ yenc,
                                                const float* __restrict__ Wd,
                                                const float* __restrict__ bd,
                                                float* __restrict__ out) {
    const int n0   = blockIdx.x * 64;
    const int t    = threadIdx.x;
    const int lane = t & 63;
    const int w    = t >> 6;
    const int l15  = lane & 15;
    const int quad = lane >> 4;
    const int m0   = w * 64;

    const unsigned short* ap[4];
#pragma unroll
    for (int mt = 0; mt < 4; ++mt)
        ap[mt] = yenc + (long)(m0 + mt * 16 + l15) * FPAD + quad * 8;
    const float* bp[4];
#pragma unroll
    for (int nt = 0; nt < 4; ++nt)
        bp[nt] = Wd + (long)(n0 + nt * 16 + l15) * FEAT + quad * 8;

    f32x4 acc[4][4];
#pragma unroll
    for (int mt = 0; mt < 4; ++mt)
#pragma unroll
        for (int nt = 0; nt < 4; ++nt) { f32x4 z = {0.f, 0.f, 0.f, 0.f}; acc[mt][nt] = z; }

    for (int k = 0; k < 1472; k += 32) {
        short8 a[4];
#pragma unroll
        for (int mt = 0; mt < 4; ++mt)
            a[mt] = *(const short8*)(ap[mt] + k);
        short8 bb[4];
#pragma unroll
        for (int nt = 0; nt < 4; ++nt) {
            const float4 b0 = *(const float4*)(bp[nt] + k);
            const float4 b1 = *(const float4*)(bp[nt] + k + 4);
            bb[nt] = cvt8(b0, b1);
        }
#pragma unroll
        for (int mt = 0; mt < 4; ++mt)
#pragma unroll
            for (int nt = 0; nt < 4; ++nt)
                acc[mt][nt] = __builtin_amdgcn_mfma_f32_16x16x32_bf16(a[mt], bb[nt], acc[mt][nt], 0, 0, 0);
    }
    {   // tail step k=1472: covers K 1472..1503; A is zero for K>=1500, so the
        // few garbage B elements (next row / clamped) multiply by zero.
        const float* lim = Wd + (long)IN * FEAT - 4;
        short8 a[4];
#pragma unroll
        for (int mt = 0; mt < 4; ++mt)
            a[mt] = *(const short8*)(ap[mt] + 1472);
        short8 bb[4];
#pragma unroll
        for (int nt = 0; nt < 4; ++nt) {
            const float* p0 = bp[nt] + 1472;
            const float* p1 = p0 + 4;
            if (p1 > lim) p1 = lim;                 // only last row's quad3
            bb[nt] = cvt8(*(const float4*)p0, *(const float4*)p1);
        }
#pragma unroll
        for (int mt = 0; mt < 4; ++mt)
#pragma unroll
            for (int nt = 0; nt < 4; ++nt)
                acc[mt][nt] = __builtin_amdgcn_mfma_f32_16x16x32_bf16(a[mt], bb[nt], acc[mt][nt], 0, 0, 0);
    }

    // epilogue: bias + sigmoid, direct store
#pragma unroll
    for (int nt = 0; nt < 4; ++nt) {
        const int col = n0 + nt * 16 + l15;
        const float bias = bd[col];
#pragma unroll
        for (int mt = 0; mt < 4; ++mt) {
            const int row = m0 + mt * 16 + quad * 4;
#pragma unroll
            for (int r = 0; r < 4; ++r) {
                float v = acc[mt][nt][r] + bias;
                out[(long)(row + r) * IN + col] = 1.0f / (1.0f + __expf(-v));
            }
        }
    }
}

extern "C" void kernel_launch(void* const* d_in, const int* in_sizes, int n_in,
                              void* d_out, int out_size, void* d_ws, size_t ws_size,
                              hipStream_t stream) {
    const float* x  = (const float*)d_in[0];
    const float* We = (const float*)d_in[1];
    const float* be = (const float*)d_in[2];
    const float* Wd = (const float*)d_in[3];
    const float* bd = (const float*)d_in[4];
    float* out = (float*)d_out;

    char* ws = (char*)d_ws;
    float* preact        = (float*)ws;                        // 1,536,000 B
    float* rn2           = (float*)(ws + 1536000);            // 6,000 B (pad to 1544192)
    unsigned short* yenc = (unsigned short*)(ws + 1544192);   // 786,432 B -> ends 2,330,624
    unsigned short* xbf  = (unsigned short*)(ws + 2330624);   // 14,450,688 B -> ends 16,781,312

    hipMemsetAsync(ws, 0, 1544192, stream);                   // preact + rn2
    hipMemsetAsync(out + 7225344, 0, 4, stream);              // jac slot

    cvt_x<<<7056, 256, 0, stream>>>(x, xbf);
    enc_gemm<<<dim3(24, 42), 256, 0, stream>>>(xbf, We, preact, rn2);
    act_jac<<<dim3(6, 256), 256, 0, stream>>>(preact, be, rn2, yenc, out + 7225344);
    dec_gemm<<<441, 256, 0, stream>>>(yenc, Wd, bd, out);
}